// Round 14
// baseline (267.723 us; speedup 1.0000x reference)
//
#include <hip/hip_runtime.h>
#include <stdint.h>

#define VOCAB 28996
#define EMBED 512
#define NROWS 8192
#define VPAD  29056  /* 227 * 128 */
#define LOG2E 1.4426950408889634f
#define WSCALE 16.0f
#define INV_WSCALE_L2E (LOG2E / 16.0f)

typedef __attribute__((ext_vector_type(8)))  int   i32x8;
typedef __attribute__((ext_vector_type(16))) float f32x16;

// pack 4 floats -> 4 x fp8 e4m3 (OCP, RNE, saturating) in one i32
__device__ __forceinline__ int pk_fp8x4(float a, float b, float c, float d) {
  int r = __builtin_amdgcn_cvt_pk_fp8_f32(a, b, 0, false);
  r = __builtin_amdgcn_cvt_pk_fp8_f32(c, d, r, true);
  return r;
}

__device__ __forceinline__ int pk_fp8x4v(float4 v, float s) {
  return pk_fp8x4(v.x * s, v.y * s, v.z * s, v.w * s);
}

// ---- transposed-fragment address: byte offset of (row r, k) in a buffer
// stored in MFMA-fragment order:
//   rb = r>>5 (32-row block), kb = k>>6 (64-B k-block),
//   lane = ((k>>5)&1)*32 + (r&31), j = k&31
//   addr = (rb*8 + kb)*2048 + lane*32 + j
// A wave's fragment load (fixed rb,kb) = lane*32 -> 2048 contiguous bytes.
__device__ __forceinline__ size_t frag_addr(int r, int k) {
  return ((size_t)((r >> 5) * 8 + (k >> 6)) << 11) +
         ((((k >> 5) & 1) * 32 + (r & 31)) << 5) + (k & 31);
}

// ---- fused prep (r12/r13-verified): cvt writes FRAGMENT-ORDER xb/wb ----
// blocks [0,2048):    py  (1 wave/row, 4 rows/block)  [latency; runs first]
// blocks [2048,5680): W*16 -> fp8, pad to VPAD  (VPAD*512/16/256 = 3632)
// blocks [5680,6704): x -> fp8                  (8192*512/16/256 = 1024)
// blocks [6704,6736): zero sg
__global__ void __launch_bounds__(256)
prep_kernel(const float* __restrict__ x, const float* __restrict__ W,
            const float* __restrict__ b, const int* __restrict__ y,
            int* __restrict__ xb, int* __restrict__ wb,
            float* __restrict__ py, float* __restrict__ sg) {
  const int bid = blockIdx.x;
  if (bid < 2048) {                        // ---- py: e^{x.W[y]+b[y]}, fp32 exact ----
    const int row  = (bid * 256 + threadIdx.x) >> 6;
    const int lane = threadIdx.x & 63;
    const int yr = y[row];
    const float4* xr = (const float4*)(x + (size_t)row * EMBED);
    const float4* wr = (const float4*)(W + (size_t)yr * EMBED);
    float d = 0.f;
#pragma unroll
    for (int t = 0; t < 2; ++t) {
      float4 a = xr[lane * 2 + t], c = wr[lane * 2 + t];
      d += a.x * c.x + a.y * c.y + a.z * c.z + a.w * c.w;
    }
#pragma unroll
    for (int m = 1; m < 64; m <<= 1) d += __shfl_xor(d, m);
    if (lane == 0) py[row] = __expf(d + b[yr]);
  } else if (bid < 5680) {                 // ---- cvt W*16 -> fp8, frag order ----
    int i = ((bid - 2048) * 256 + threadIdx.x) * 16;  // float index
    const int VK = VOCAB * EMBED;                     // multiple of 16
    const int r = i >> 9, k = i & 511;
    int4 o;
    if (i < VK) {
      const float4* p = (const float4*)(W + i);
      o.x = pk_fp8x4v(p[0], WSCALE);
      o.y = pk_fp8x4v(p[1], WSCALE);
      o.z = pk_fp8x4v(p[2], WSCALE);
      o.w = pk_fp8x4v(p[3], WSCALE);
    } else { o.x = 0; o.y = 0; o.z = 0; o.w = 0; }
    *(int4*)((uint8_t*)wb + frag_addr(r, k)) = o;
  } else if (bid < 6704) {                 // ---- cvt x -> fp8, frag order ----
    int i = ((bid - 5680) * 256 + threadIdx.x) * 16;
    const int r = i >> 9, k = i & 511;
    const float4* p = (const float4*)(x + i);
    int4 o;
    o.x = pk_fp8x4v(p[0], 1.f);
    o.y = pk_fp8x4v(p[1], 1.f);
    o.z = pk_fp8x4v(p[2], 1.f);
    o.w = pk_fp8x4v(p[3], 1.f);
    *(int4*)((uint8_t*)xb + frag_addr(r, k)) = o;
  } else {                                 // ---- zero sg ----
    int i = (bid - 6704) * 256 + threadIdx.x;
    sg[i] = 0.f;
  }
}

// ---- fused GEMM (16*logits = x . (16W)^T, MX-fp8 32x32x64) + row-sum exp ----
// Round-14 = r13's no-LDS/no-barrier fragment-order structure with the
// 128x256 BLOCK TILE (wave tile 128x64 = 4(ii) x 2(jj) of 32x32).
// Why: r13's ledger shows the L1 pipe oversubscribed vs the matrix pipe
// (per SIMD per phase: ~384 cy L1 return vs 275 cy MFMA; 3.72 GB total
// fragment traffic = 55% of L1 ceiling at 171 us). Wave tile 128x64 cuts
// bytes/MFMA 2.0KB -> 1.5KB (traffic ~ (a+b)/(a*b)), total 2.79 GB,
// L1-bound floor ~68 us. 8 phases x {6 coalesced 2048-B loads, 8 MFMAs}
// with NAMED 2-deep phase buffers (compile-time indexed, rule 20).
// Regs: acc 128 (AGPR) + 2x48 frag VGPR + addr ~= 244 < 256 budget of
// launch_bounds(256,2) (precedent r2/r3: 236 at (512,2), zero spill;
// r6's spill was 213-in-168 — different regime). 2 blocks/CU.
// B-tail: grid.y=114 covers cols to 29183 > VPAD-1; clamp cb to 907
// (reads valid finite fp8 — saturating cvt emits no NaN encodings) and
// bias=-1e30 for col>=VOCAB zeroes those exp contributions (r7-proven).
__global__ void __launch_bounds__(256, 2)
gemm_stats_kernel(const uint8_t* __restrict__ xb, const uint8_t* __restrict__ wb,
                  const float* __restrict__ bias, float* __restrict__ sg) {
  const int tid  = threadIdx.x;
  const int lane = tid & 63;
  const int w    = tid >> 6;       // wave 0..3
  const int l31  = lane & 31;
  const int h    = lane >> 5;      // k-half for 32x32 operands
  const int wc   = w * 64;         // wave col offset (rows: all 128)
  const int rowBase = blockIdx.x * 128;  // x rows     (grid.x = 64)
  const int colBase = blockIdx.y * 256;  // vocab cols (grid.y = 114)

  // fragment-order base pointers: 32-row block index * 16384 + lane*32
  const uint8_t* pa = xb + ((size_t)(blockIdx.x * 4) << 14) + lane * 32;
  const int cb0 = blockIdx.y * 8 + w * 2;          // B 32-col block for jj=0
  const int c0c = cb0     < 907 ? cb0     : 907;   // tail clamp (see header)
  const int c1c = cb0 + 1 < 907 ? cb0 + 1 : 907;
  const uint8_t* pb0 = wb + ((size_t)c0c << 14) + lane * 32;
  const uint8_t* pb1 = wb + ((size_t)c1c << 14) + lane * 32;

  f32x16 acc[4][2];
#pragma unroll
  for (int i = 0; i < 4; ++i)
#pragma unroll
    for (int j = 0; j < 2; ++j)
#pragma unroll
      for (int r = 0; r < 16; ++r) acc[i][j][r] = 0.f;

  // phase p = kt*2+kk (0..7): fragment byte offset p*2048
  auto loadPh = [&](int p, i32x8* aq, i32x8* bq) {
    const size_t off = (size_t)p << 11;
    bq[0] = *(const i32x8*)(pb0 + off);
    bq[1] = *(const i32x8*)(pb1 + off);
#pragma unroll
    for (int ii = 0; ii < 4; ++ii)
      aq[ii] = *(const i32x8*)(pa + ((size_t)ii << 14) + off);
  };
  auto mmaPh = [&](const i32x8* aq, const i32x8* bq) {
#pragma unroll
    for (int ii = 0; ii < 4; ++ii) {
      acc[ii][0] = __builtin_amdgcn_mfma_scale_f32_32x32x64_f8f6f4(
          aq[ii], bq[0], acc[ii][0], 0, 0, 0, 0x7F7F7F7F, 0, 0x7F7F7F7F);
      acc[ii][1] = __builtin_amdgcn_mfma_scale_f32_32x32x64_f8f6f4(
          aq[ii], bq[1], acc[ii][1], 0, 0, 0, 0x7F7F7F7F, 0, 0x7F7F7F7F);
    }
  };

  i32x8 aqA[4], bqA[2], aqB[4], bqB[2];   // two named phase buffers
  loadPh(0, aqA, bqA);
#pragma unroll
  for (int p = 0; p < 8; ++p) {
    if ((p & 1) == 0) {
      if (p < 7) loadPh(p + 1, aqB, bqB);  // prefetch odd phase
      mmaPh(aqA, bqA);
    } else {
      if (p < 7) loadPh(p + 1, aqA, bqA);  // prefetch even phase
      mmaPh(aqB, bqB);
    }
  }

  // ---- epilogue: s_row += sum_j exp(acc/16 + bias)  (r7-verified, 128x64) ----
  // 32x32 C/D layout (m74/m101): col = lane&31, row = (reg&3)+8*(reg>>2)+4*h
  float bvl[2];
#pragma unroll
  for (int ni = 0; ni < 2; ++ni) {
    const int col = colBase + wc + ni * 32 + l31;
    bvl[ni] = (col < VOCAB) ? bias[col] * LOG2E : -1e30f;
  }

#pragma unroll
  for (int p = 0; p < 2; ++p) {            // p: 64-row half of the wave tile
    float sp[32];  // v = q*16 + reg, mi = p*2 + q
#pragma unroll
    for (int q = 0; q < 2; ++q)
#pragma unroll
      for (int r = 0; r < 16; ++r)
        sp[q * 16 + r] =
            exp2f(fmaf(acc[p * 2 + q][0][r], INV_WSCALE_L2E, bvl[0])) +
            exp2f(fmaf(acc[p * 2 + q][1][r], INV_WSCALE_L2E, bvl[1]));

    // stacking reduction over the 32 cols (xor 1..16 stays within the h-half);
    // ends with lane holding the full col-sum for value index v == (lane&31).
    float t1[16];
#pragma unroll
    for (int u = 0; u < 16; ++u) {
      float a = sp[2 * u]     + __shfl_xor(sp[2 * u],     1);
      float b = sp[2 * u + 1] + __shfl_xor(sp[2 * u + 1], 1);
      t1[u] = (l31 & 1) ? b : a;
    }
    float t2[8];
#pragma unroll
    for (int u = 0; u < 8; ++u) {
      float a = t1[2 * u]     + __shfl_xor(t1[2 * u],     2);
      float b = t1[2 * u + 1] + __shfl_xor(t1[2 * u + 1], 2);
      t2[u] = (l31 & 2) ? b : a;
    }
    float t3[4];
#pragma unroll
    for (int u = 0; u < 4; ++u) {
      float a = t2[2 * u]     + __shfl_xor(t2[2 * u],     4);
      float b = t2[2 * u + 1] + __shfl_xor(t2[2 * u + 1], 4);
      t3[u] = (l31 & 4) ? b : a;
    }
    float t4[2];
#pragma unroll
    for (int u = 0; u < 2; ++u) {
      float a = t3[2 * u]     + __shfl_xor(t3[2 * u],     8);
      float b = t3[2 * u + 1] + __shfl_xor(t3[2 * u + 1], 8);
      t4[u] = (l31 & 8) ? b : a;
    }
    {
      float a = t4[0] + __shfl_xor(t4[0], 16);
      float b = t4[1] + __shfl_xor(t4[1], 16);
      float ssum = (l31 & 16) ? b : a;
      const int v = l31;                 // q = v>>4, reg = v&15
      const int row = rowBase + p * 64 + (v >> 4) * 32 +
                      (v & 3) + 8 * ((v & 15) >> 2) + 4 * h;
      atomicAdd(&sg[row], ssum);
    }
  }
}

// ---- final: loss = log(V+1) - mean(py/s)  (q-term ~7e-10, dropped) ----
__global__ void __launch_bounds__(1024)
finalize_kernel(const float* __restrict__ sg, const float* __restrict__ py,
                float* __restrict__ out) {
  __shared__ float red[1024];
  float a = 0.f;
  for (int i = threadIdx.x; i < NROWS; i += 1024)
    a += py[i] / sg[i];
  red[threadIdx.x] = a;
  __syncthreads();
  for (int st = 512; st > 0; st >>= 1) {
    if (threadIdx.x < st) red[threadIdx.x] += red[threadIdx.x + st];
    __syncthreads();
  }
  if (threadIdx.x == 0)
    out[0] = logf((float)(VOCAB + 1)) - red[0] * (1.f / (float)NROWS);
}

extern "C" void kernel_launch(void* const* d_in, const int* in_sizes, int n_in,
                              void* d_out, int out_size, void* d_ws, size_t ws_size,
                              hipStream_t stream) {
  const float* x = (const float*)d_in[0];
  const int*   y = (const int*)d_in[1];
  const float* W = (const float*)d_in[2];
  const float* b = (const float*)d_in[3];

  char* ws = (char*)d_ws;
  uint8_t* xb = (uint8_t*)ws;                             // 4,194,304 B (frag order)
  uint8_t* wb = (uint8_t*)(ws + 4194304);                 // 14,876,672 B (frag order)
  float*   sg = (float*)(ws + 4194304 + 14876672);        // 32 KiB
  float*   py = sg + NROWS;                               // 32 KiB

  prep_kernel<<<6736, 256, 0, stream>>>(x, W, b, y, (int*)xb, (int*)wb, py, sg);
  gemm_stats_kernel<<<dim3(64, 114), 256, 0, stream>>>(xb, wb, b, sg);
  finalize_kernel<<<1, 1024, 0, stream>>>(sg, py, (float*)d_out);
}